// Round 1
// baseline (286.114 us; speedup 1.0000x reference)
//
#include <hip/hip_runtime.h>
#include <math.h>

#define NN 4096
#define NE 16384
#define NG 64

// ---- ws layout (float offsets) ----
#define OFF_DEG   0         // 4096   (deg, norm computed on the fly)
#define OFF_H1    4096      // 4096*32
#define OFF_H2    135168    // 4096*64
#define OFF_H3    397312    // 4096*128
#define OFF_ST1   921600    // 64
#define OFF_ST2   921664    // 128
#define OFF_ST3   921792    // 256
#define OFF_POOL  922048    // 64*128
#define OFF_WET1  930240    // 8*16*32
#define OFF_BET1  934336    // 512
#define OFF_WET2  934848    // 8*32*64
#define OFF_BET2  951232    // 2048
#define OFF_WET3  953280    // 8*64*128
#define OFF_BET3  1018816   // 8192
#define ZERO_FLOATS 930240  // zero accumulators only (not transposed weights)

// ---------------- prep: transpose We/be + degree ----------------
__device__ __forceinline__ void tr_we(const float* We, float* WeT, int CIN, int COUT, int t) {
    int per = CIN * COUT;
    int f = t / per; int r = t - f * per;
    int o = r / CIN; int i = r - o * CIN;
    WeT[(f * CIN + i) * COUT + o] = We[t];
}
__device__ __forceinline__ void tr_be(const float* be, float* beT, int CIN, int COUT, int t) {
    int o = t / CIN; int i = t - o * CIN;
    beT[i * COUT + o] = be[t];
}

__global__ __launch_bounds__(256) void k_prep(
    const float* __restrict__ We1, const float* __restrict__ be1,
    const float* __restrict__ We2, const float* __restrict__ be2,
    const float* __restrict__ We3, const float* __restrict__ be3,
    const int* __restrict__ ei, float* __restrict__ ws)
{
    int t = blockIdx.x * 256 + threadIdx.x;
    if (t < 4096)  { tr_we(We1, ws + OFF_WET1, 16, 32, t); return; }
    t -= 4096;
    if (t < 512)   { tr_be(be1, ws + OFF_BET1, 16, 32, t); return; }
    t -= 512;
    if (t < 16384) { tr_we(We2, ws + OFF_WET2, 32, 64, t); return; }
    t -= 16384;
    if (t < 2048)  { tr_be(be2, ws + OFF_BET2, 32, 64, t); return; }
    t -= 2048;
    if (t < 65536) { tr_we(We3, ws + OFF_WET3, 64, 128, t); return; }
    t -= 65536;
    if (t < 8192)  { tr_be(be3, ws + OFF_BET3, 64, 128, t); return; }
    t -= 8192;
    if (t < NE)    { atomicAdd(&ws[OFF_DEG + ei[t]], 1.0f); }
}

// ---------------- edge message + scatter ----------------
// msg[e,o] = norm[src] * sum_i x[src,i] * (beT[i,o] + sum_f ea[e,f]*WeT[f,i,o])
// block = TO*EL threads; TE = EL*KE edges per block; blockIdx.y = o-chunk
template<int CIN, int COUT, int TO, int EL, int KE>
__global__ __launch_bounds__(TO*EL) void k_edge(
    const float* __restrict__ xin, const float* __restrict__ eattr,
    const int* __restrict__ ei, const float* __restrict__ deg,
    const float* __restrict__ WeT, const float* __restrict__ beT,
    float* __restrict__ hout)
{
    constexpr int TE = EL * KE;
    constexpr int NT = TO * EL;
    constexpr int CINP = CIN | 1;   // odd-pad rows -> conflict-free LDS
    __shared__ float sWe[8 * CIN * TO];
    __shared__ float sBe[CIN * TO];
    __shared__ float sX[TE * CINP];
    __shared__ float sEa[TE * 8];
    __shared__ float sNorm[TE];
    __shared__ int   sDst[TE];
    const int tid = threadIdx.x;
    const int ebase = blockIdx.x * TE;
    const int obase = blockIdx.y * TO;

    for (int t = tid; t < 8 * CIN * TO; t += NT) {
        int fi = t / TO, o = t % TO;
        sWe[t] = WeT[fi * COUT + obase + o];
    }
    for (int t = tid; t < CIN * TO; t += NT) {
        int i = t / TO, o = t % TO;
        sBe[t] = beT[i * COUT + obase + o];
    }
    for (int t = tid; t < TE * CIN; t += NT) {
        int el = t / CIN, i = t % CIN;
        int s = ei[ebase + el];
        sX[el * CINP + i] = xin[s * CIN + i];
    }
    for (int t = tid; t < TE * 8; t += NT) sEa[t] = eattr[ebase * 8 + t];
    if (tid < TE) {
        int s = ei[ebase + tid];
        float d = deg[s];
        sNorm[tid] = d > 0.f ? 1.f / d : 0.f;
        sDst[tid] = ei[NE + ebase + tid];
    }
    __syncthreads();

    const int o  = tid % TO;
    const int el = tid / TO;

    float ea[KE][8];
#pragma unroll
    for (int k = 0; k < KE; ++k)
#pragma unroll
        for (int f = 0; f < 8; ++f)
            ea[k][f] = sEa[(el * KE + k) * 8 + f];

    float acc[KE];
#pragma unroll
    for (int k = 0; k < KE; ++k) acc[k] = 0.f;

    for (int i = 0; i < CIN; ++i) {
        float w[8];
#pragma unroll
        for (int f = 0; f < 8; ++f) w[f] = sWe[(f * CIN + i) * TO + o];
        float bw = sBe[i * TO + o];
#pragma unroll
        for (int k = 0; k < KE; ++k) {
            float th = bw;
#pragma unroll
            for (int f = 0; f < 8; ++f) th += ea[k][f] * w[f];
            acc[k] += th * sX[(el * KE + k) * CINP + i];
        }
    }
#pragma unroll
    for (int k = 0; k < KE; ++k) {
        int e = el * KE + k;
        atomicAdd(&hout[sDst[e] * COUT + obase + o], acc[k] * sNorm[e]);
    }
}

// ---------------- node: residual + bias, accumulate BN stats ----------------
template<int CIN, int COUT, int KN>
__global__ __launch_bounds__(256) void k_node(
    const float* __restrict__ xin, const float* __restrict__ Wr,
    const float* __restrict__ br, const float* __restrict__ bias,
    float* __restrict__ h, float* __restrict__ st)
{
    constexpr int NL = 256 / COUT;
    constexpr int NB = NL * KN;
    constexpr int CINP = CIN | 1;
    __shared__ float sWr[CIN * COUT];
    __shared__ float sX[NB * CINP];
    __shared__ float sred[256];
    const int tid = threadIdx.x;
    const int nbase = blockIdx.x * NB;

    for (int t = tid; t < CIN * COUT; t += 256) sWr[t] = Wr[t];
    for (int t = tid; t < NB * CIN; t += 256) {
        int r = t / CIN, i = t % CIN;
        sX[r * CINP + i] = xin[(nbase + r) * CIN + i];
    }
    __syncthreads();

    const int o = tid % COUT;
    const int nl = tid / COUT;
    const float addc = bias[o] + br[o];
    float sum = 0.f, sumsq = 0.f;
    for (int k = 0; k < KN; ++k) {
        int r = nl * KN + k;
        float a = addc;
        for (int i = 0; i < CIN; ++i)
            a += sX[r * CINP + i] * sWr[i * COUT + o];
        int gi = (nbase + r) * COUT + o;
        float hv = h[gi] + a;
        h[gi] = hv;
        sum += hv; sumsq += hv * hv;
    }
    sred[tid] = sum;
    __syncthreads();
    if (tid < COUT) {
        float s = 0.f;
        for (int g2 = 0; g2 < NL; ++g2) s += sred[g2 * COUT + tid];
        atomicAdd(&st[tid], s);
    }
    __syncthreads();
    sred[tid] = sumsq;
    __syncthreads();
    if (tid < COUT) {
        float s = 0.f;
        for (int g2 = 0; g2 < NL; ++g2) s += sred[g2 * COUT + tid];
        atomicAdd(&st[COUT + tid], s);
    }
}

// ---------------- BN (biased var) + PReLU, in place ----------------
template<int COUT>
__global__ __launch_bounds__(256) void k_bn(
    float* __restrict__ h, const float* __restrict__ st,
    const float* __restrict__ g, const float* __restrict__ b,
    const float* __restrict__ a)
{
    int idx = blockIdx.x * 256 + threadIdx.x;
    int o = idx % COUT;
    float mean = st[o] * (1.f / NN);
    float var = st[COUT + o] * (1.f / NN) - mean * mean;
    var = fmaxf(var, 0.f);
    float inv = rsqrtf(var + 1e-5f);
    float v = (h[idx] - mean) * inv * g[o] + b[o];
    h[idx] = v >= 0.f ? v : a[0] * v;
}

// ---------------- gated pooling: sigmoid(hWi+bi)*tanh(hWj+bj) scatter ----------------
__global__ __launch_bounds__(256) void k_pool(
    const float* __restrict__ h3, const int* __restrict__ batch,
    const float* __restrict__ Wi, const float* __restrict__ bi,
    const float* __restrict__ Wj, const float* __restrict__ bj,
    float* __restrict__ pooled)
{
    constexpr int KN = 8, NB = 16;
    __shared__ float sH[NB * 128];
    __shared__ int sB[NB];
    const int tid = threadIdx.x;
    const int nbase = blockIdx.x * NB;
    for (int t = tid; t < NB * 128; t += 256) sH[t] = h3[nbase * 128 + t];
    if (tid < NB) sB[tid] = batch[nbase + tid];
    __syncthreads();

    const int o = tid % 128, nl = tid / 128;
    float gacc[KN], facc[KN];
#pragma unroll
    for (int k = 0; k < KN; ++k) { gacc[k] = 0.f; facc[k] = 0.f; }
    for (int i = 0; i < 128; ++i) {
        float wi = Wi[i * 128 + o], wj = Wj[i * 128 + o];
#pragma unroll
        for (int k = 0; k < KN; ++k) {
            float hv = sH[(nl * KN + k) * 128 + i];
            gacc[k] += hv * wi;
            facc[k] += hv * wj;
        }
    }
    float bio = bi[o], bjo = bj[o];
#pragma unroll
    for (int k = 0; k < KN; ++k) {
        int r = nl * KN + k;
        float gate = 1.f / (1.f + expf(-(gacc[k] + bio)));
        float feat = tanhf(facc[k] + bjo);
        atomicAdd(&pooled[sB[r] * 128 + o], gate * feat);
    }
}

// ---------------- final: tanh(pooled) @ Wfc + bfc, split halves ----------------
__global__ __launch_bounds__(256) void k_final(
    const float* __restrict__ pooled, const float* __restrict__ Wfc,
    const float* __restrict__ bfc, float* __restrict__ out)
{
    __shared__ float sP[128];
    const int g = blockIdx.x, c = threadIdx.x;
    if (c < 128) sP[c] = tanhf(pooled[g * 128 + c]);
    __syncthreads();
    float z = bfc[c];
    for (int i = 0; i < 128; ++i) z += sP[i] * Wfc[i * 256 + c];
    int oidx = (c < 128) ? (g * 128 + c) : (NG * 128 + g * 128 + (c - 128));
    out[oidx] = z;
}

extern "C" void kernel_launch(void* const* d_in, const int* in_sizes, int n_in,
                              void* d_out, int out_size, void* d_ws, size_t ws_size,
                              hipStream_t stream)
{
    (void)in_sizes; (void)n_in; (void)out_size; (void)ws_size;
    const float* x     = (const float*)d_in[0];
    const float* eattr = (const float*)d_in[1];
    const int*   ei    = (const int*)d_in[2];
    const int*   batch = (const int*)d_in[3];
    const float* We1 = (const float*)d_in[4];
    const float* be1 = (const float*)d_in[5];
    const float* bias1 = (const float*)d_in[6];
    const float* Wr1 = (const float*)d_in[7];
    const float* br1 = (const float*)d_in[8];
    const float* bg1 = (const float*)d_in[9];
    const float* bb1 = (const float*)d_in[10];
    const float* a1  = (const float*)d_in[11];
    const float* We2 = (const float*)d_in[12];
    const float* be2 = (const float*)d_in[13];
    const float* bias2 = (const float*)d_in[14];
    const float* Wr2 = (const float*)d_in[15];
    const float* br2 = (const float*)d_in[16];
    const float* bg2 = (const float*)d_in[17];
    const float* bb2 = (const float*)d_in[18];
    const float* a2  = (const float*)d_in[19];
    const float* We3 = (const float*)d_in[20];
    const float* be3 = (const float*)d_in[21];
    const float* bias3 = (const float*)d_in[22];
    const float* Wr3 = (const float*)d_in[23];
    const float* br3 = (const float*)d_in[24];
    const float* bg3 = (const float*)d_in[25];
    const float* bb3 = (const float*)d_in[26];
    const float* a3  = (const float*)d_in[27];
    const float* Wi  = (const float*)d_in[28];
    const float* bi  = (const float*)d_in[29];
    const float* Wj  = (const float*)d_in[30];
    const float* bj  = (const float*)d_in[31];
    const float* Wfc = (const float*)d_in[32];
    const float* bfc = (const float*)d_in[33];
    float* ws  = (float*)d_ws;
    float* out = (float*)d_out;

    hipMemsetAsync(d_ws, 0, (size_t)ZERO_FLOATS * sizeof(float), stream);
    k_prep<<<442, 256, 0, stream>>>(We1, be1, We2, be2, We3, be3, ei, ws);

    // layer 1: cin=16, cout=32
    k_edge<16, 32, 32, 8, 8><<<dim3(NE / 64, 1), 256, 0, stream>>>(
        x, eattr, ei, ws + OFF_DEG, ws + OFF_WET1, ws + OFF_BET1, ws + OFF_H1);
    k_node<16, 32, 8><<<NN / 64, 256, 0, stream>>>(x, Wr1, br1, bias1, ws + OFF_H1, ws + OFF_ST1);
    k_bn<32><<<NN * 32 / 256, 256, 0, stream>>>(ws + OFF_H1, ws + OFF_ST1, bg1, bb1, a1);

    // layer 2: cin=32, cout=64
    k_edge<32, 64, 32, 8, 8><<<dim3(NE / 64, 2), 256, 0, stream>>>(
        ws + OFF_H1, eattr, ei, ws + OFF_DEG, ws + OFF_WET2, ws + OFF_BET2, ws + OFF_H2);
    k_node<32, 64, 8><<<NN / 32, 256, 0, stream>>>(ws + OFF_H1, Wr2, br2, bias2, ws + OFF_H2, ws + OFF_ST2);
    k_bn<64><<<NN * 64 / 256, 256, 0, stream>>>(ws + OFF_H2, ws + OFF_ST2, bg2, bb2, a2);

    // layer 3: cin=64, cout=128
    k_edge<64, 128, 16, 16, 4><<<dim3(NE / 64, 8), 256, 0, stream>>>(
        ws + OFF_H2, eattr, ei, ws + OFF_DEG, ws + OFF_WET3, ws + OFF_BET3, ws + OFF_H3);
    k_node<64, 128, 8><<<NN / 16, 256, 0, stream>>>(ws + OFF_H2, Wr3, br3, bias3, ws + OFF_H3, ws + OFF_ST3);
    k_bn<128><<<NN * 128 / 256, 256, 0, stream>>>(ws + OFF_H3, ws + OFF_ST3, bg3, bb3, a3);

    // pooling + head
    k_pool<<<NN / 16, 256, 0, stream>>>(ws + OFF_H3, batch, Wi, bi, Wj, bj, ws + OFF_POOL);
    k_final<<<NG, 256, 0, stream>>>(ws + OFF_POOL, Wfc, bfc, out);
}

// Round 2
// 255.949 us; speedup vs baseline: 1.1179x; 1.1179x over previous
//
#include <hip/hip_runtime.h>
#include <math.h>

#define NN 4096
#define NE 16384
#define NG 64

// ---- ws layout (float offsets) ----
#define OFF_DEG   0         // 4096
#define OFF_H1    4096      // 4096*32
#define OFF_H2    135168    // 4096*64
#define OFF_H3    397312    // 4096*128
#define OFF_ST1   921600    // 64
#define OFF_ST2   921664    // 128
#define OFF_ST3   921792    // 256
#define OFF_POOL  922048    // 64*128
#define OFF_WC1   930240    // 16*288  = 4608
#define OFF_WC2   934848    // 32*576  = 18432
#define OFF_WC3   953280    // 64*1152 = 73728
#define OFF_Y     1027008   // 4096*1152 = 4718592 (reused across layers)
#define ZERO_FLOATS 930240  // zero deg/h/stats/pool only

// ---------------- prep: build Wcat (We + be as 9th filter) + degree ----------------
// Wcat[i*(9*COUT) + f*COUT + o] = f<8 ? We[f*CIN*COUT + o*CIN + i] : be[o*CIN + i]
__device__ __forceinline__ void tr_wcat(const float* We, const float* be,
                                        float* Wcat, int CIN, int COUT, int t) {
    int nine = 9 * COUT;
    int i = t / nine; int r = t - i * nine;
    int f = r / COUT; int o = r - f * COUT;
    Wcat[t] = (f < 8) ? We[f * CIN * COUT + o * CIN + i] : be[o * CIN + i];
}

__global__ __launch_bounds__(256) void k_prep(
    const float* __restrict__ We1, const float* __restrict__ be1,
    const float* __restrict__ We2, const float* __restrict__ be2,
    const float* __restrict__ We3, const float* __restrict__ be3,
    const int* __restrict__ ei, float* __restrict__ ws)
{
    int t = blockIdx.x * 256 + threadIdx.x;
    if (t < 4608)  { tr_wcat(We1, be1, ws + OFF_WC1, 16, 32, t); return; }
    t -= 4608;
    if (t < 18432) { tr_wcat(We2, be2, ws + OFF_WC2, 32, 64, t); return; }
    t -= 18432;
    if (t < 73728) { tr_wcat(We3, be3, ws + OFF_WC3, 64, 128, t); return; }
    t -= 73728;
    if (t < NE)    { atomicAdd(&ws[OFF_DEG + ei[t]], 1.0f); }
}

// ---------------- proj GEMM: Y[n, col] = norm[n] * sum_i A[n,i] * B[i,col] ----------------
// BM=64, BN=64, 256 threads, 4x4 per thread, K fully staged in LDS
template<int K>
__global__ __launch_bounds__(256) void k_proj(
    const float* __restrict__ A,    // [4096, K]
    const float* __restrict__ B,    // [K, Ncols]
    const float* __restrict__ deg,
    float* __restrict__ Y, int Ncols)
{
    __shared__ float sA[K][68];   // sA[i][m] (transposed A tile)
    __shared__ float sB[K][68];
    const int tid = threadIdx.x;
    const int m0 = blockIdx.x * 64;
    const int n0 = blockIdx.y * 64;

    for (int t = tid; t < 64 * K; t += 256) {
        int m = t / K, i = t - m * K;
        sA[i][m] = A[(m0 + m) * K + i];
    }
    for (int t = tid; t < 64 * K; t += 256) {
        int i = t / 64, n = t - i * 64;
        int col = n0 + n;
        sB[i][n] = (col < Ncols) ? B[i * Ncols + col] : 0.f;
    }
    __syncthreads();

    const int tn = tid % 16, tm = tid / 16;
    float acc[4][4] = {{0.f}};
#pragma unroll 8
    for (int i = 0; i < K; ++i) {
        float4 a = *(const float4*)&sA[i][tm * 4];
        float4 b = *(const float4*)&sB[i][tn * 4];
        acc[0][0] += a.x * b.x; acc[0][1] += a.x * b.y; acc[0][2] += a.x * b.z; acc[0][3] += a.x * b.w;
        acc[1][0] += a.y * b.x; acc[1][1] += a.y * b.y; acc[1][2] += a.y * b.z; acc[1][3] += a.y * b.w;
        acc[2][0] += a.z * b.x; acc[2][1] += a.z * b.y; acc[2][2] += a.z * b.z; acc[2][3] += a.z * b.w;
        acc[3][0] += a.w * b.x; acc[3][1] += a.w * b.y; acc[3][2] += a.w * b.z; acc[3][3] += a.w * b.w;
    }

#pragma unroll
    for (int mm = 0; mm < 4; ++mm) {
        int m = m0 + tm * 4 + mm;
        float d = deg[m];
        float nrm = d > 0.f ? 1.f / d : 0.f;
#pragma unroll
        for (int nn = 0; nn < 4; ++nn) {
            int col = n0 + tn * 4 + nn;
            if (col < Ncols) Y[(size_t)m * Ncols + col] = acc[mm][nn] * nrm;
        }
    }
}

// ---------------- per-edge gather: h[dst,o] += sum_f ea'[e,f] * Y[src, f*COUT+o] ----------------
template<int COUT>
__global__ __launch_bounds__(256) void k_egather(
    const float* __restrict__ Y, const float* __restrict__ eattr,
    const int* __restrict__ ei, float* __restrict__ h)
{
    int idx = blockIdx.x * 256 + threadIdx.x;
    int e = idx / COUT;
    int o = idx - e * COUT;
    int src = ei[e], dst = ei[NE + e];
    const float* y = Y + (size_t)src * (9 * COUT);
    const float* ea = eattr + e * 8;
    float acc = y[8 * COUT + o];      // be-term, ea' = 1
#pragma unroll
    for (int f = 0; f < 8; ++f) acc += ea[f] * y[f * COUT + o];
    atomicAdd(&h[dst * COUT + o], acc);
}

// ---------------- node: residual + bias, accumulate BN stats ----------------
template<int CIN, int COUT, int KN>
__global__ __launch_bounds__(256) void k_node(
    const float* __restrict__ xin, const float* __restrict__ Wr,
    const float* __restrict__ br, const float* __restrict__ bias,
    float* __restrict__ h, float* __restrict__ st)
{
    constexpr int NL = 256 / COUT;
    constexpr int NB = NL * KN;
    constexpr int CINP = CIN | 1;
    __shared__ float sWr[CIN * COUT];
    __shared__ float sX[NB * CINP];
    __shared__ float sred[256];
    const int tid = threadIdx.x;
    const int nbase = blockIdx.x * NB;

    for (int t = tid; t < CIN * COUT; t += 256) sWr[t] = Wr[t];
    for (int t = tid; t < NB * CIN; t += 256) {
        int r = t / CIN, i = t - r * CIN;
        sX[r * CINP + i] = xin[(nbase + r) * CIN + i];
    }
    __syncthreads();

    const int o = tid % COUT;
    const int nl = tid / COUT;
    const float addc = bias[o] + br[o];
    float sum = 0.f, sumsq = 0.f;
    for (int k = 0; k < KN; ++k) {
        int r = nl * KN + k;
        float a = addc;
        for (int i = 0; i < CIN; ++i)
            a += sX[r * CINP + i] * sWr[i * COUT + o];
        int gi = (nbase + r) * COUT + o;
        float hv = h[gi] + a;
        h[gi] = hv;
        sum += hv; sumsq += hv * hv;
    }
    sred[tid] = sum;
    __syncthreads();
    if (tid < COUT) {
        float s = 0.f;
        for (int g2 = 0; g2 < NL; ++g2) s += sred[g2 * COUT + tid];
        atomicAdd(&st[tid], s);
    }
    __syncthreads();
    sred[tid] = sumsq;
    __syncthreads();
    if (tid < COUT) {
        float s = 0.f;
        for (int g2 = 0; g2 < NL; ++g2) s += sred[g2 * COUT + tid];
        atomicAdd(&st[COUT + tid], s);
    }
}

// ---------------- BN (biased var) + PReLU, in place ----------------
template<int COUT>
__global__ __launch_bounds__(256) void k_bn(
    float* __restrict__ h, const float* __restrict__ st,
    const float* __restrict__ g, const float* __restrict__ b,
    const float* __restrict__ a)
{
    int idx = blockIdx.x * 256 + threadIdx.x;
    int o = idx % COUT;
    float mean = st[o] * (1.f / NN);
    float var = st[COUT + o] * (1.f / NN) - mean * mean;
    var = fmaxf(var, 0.f);
    float inv = rsqrtf(var + 1e-5f);
    float v = (h[idx] - mean) * inv * g[o] + b[o];
    h[idx] = v >= 0.f ? v : a[0] * v;
}

// ---------------- gated pooling ----------------
__global__ __launch_bounds__(256) void k_pool(
    const float* __restrict__ h3, const int* __restrict__ batch,
    const float* __restrict__ Wi, const float* __restrict__ bi,
    const float* __restrict__ Wj, const float* __restrict__ bj,
    float* __restrict__ pooled)
{
    constexpr int KN = 8, NB = 16;
    __shared__ float sH[NB * 128];
    __shared__ int sB[NB];
    const int tid = threadIdx.x;
    const int nbase = blockIdx.x * NB;
    for (int t = tid; t < NB * 128; t += 256) sH[t] = h3[nbase * 128 + t];
    if (tid < NB) sB[tid] = batch[nbase + tid];
    __syncthreads();

    const int o = tid % 128, nl = tid / 128;
    float gacc[KN], facc[KN];
#pragma unroll
    for (int k = 0; k < KN; ++k) { gacc[k] = 0.f; facc[k] = 0.f; }
    for (int i = 0; i < 128; ++i) {
        float wi = Wi[i * 128 + o], wj = Wj[i * 128 + o];
#pragma unroll
        for (int k = 0; k < KN; ++k) {
            float hv = sH[(nl * KN + k) * 128 + i];
            gacc[k] += hv * wi;
            facc[k] += hv * wj;
        }
    }
    float bio = bi[o], bjo = bj[o];
#pragma unroll
    for (int k = 0; k < KN; ++k) {
        int r = nl * KN + k;
        float gate = 1.f / (1.f + expf(-(gacc[k] + bio)));
        float feat = tanhf(facc[k] + bjo);
        atomicAdd(&pooled[sB[r] * 128 + o], gate * feat);
    }
}

// ---------------- final: tanh(pooled) @ Wfc + bfc, split halves ----------------
__global__ __launch_bounds__(256) void k_final(
    const float* __restrict__ pooled, const float* __restrict__ Wfc,
    const float* __restrict__ bfc, float* __restrict__ out)
{
    __shared__ float sP[128];
    const int g = blockIdx.x, c = threadIdx.x;
    if (c < 128) sP[c] = tanhf(pooled[g * 128 + c]);
    __syncthreads();
    float z = bfc[c];
    for (int i = 0; i < 128; ++i) z += sP[i] * Wfc[i * 256 + c];
    int oidx = (c < 128) ? (g * 128 + c) : (NG * 128 + g * 128 + (c - 128));
    out[oidx] = z;
}

extern "C" void kernel_launch(void* const* d_in, const int* in_sizes, int n_in,
                              void* d_out, int out_size, void* d_ws, size_t ws_size,
                              hipStream_t stream)
{
    (void)in_sizes; (void)n_in; (void)out_size; (void)ws_size;
    const float* x     = (const float*)d_in[0];
    const float* eattr = (const float*)d_in[1];
    const int*   ei    = (const int*)d_in[2];
    const int*   batch = (const int*)d_in[3];
    const float* We1 = (const float*)d_in[4];
    const float* be1 = (const float*)d_in[5];
    const float* bias1 = (const float*)d_in[6];
    const float* Wr1 = (const float*)d_in[7];
    const float* br1 = (const float*)d_in[8];
    const float* bg1 = (const float*)d_in[9];
    const float* bb1 = (const float*)d_in[10];
    const float* a1  = (const float*)d_in[11];
    const float* We2 = (const float*)d_in[12];
    const float* be2 = (const float*)d_in[13];
    const float* bias2 = (const float*)d_in[14];
    const float* Wr2 = (const float*)d_in[15];
    const float* br2 = (const float*)d_in[16];
    const float* bg2 = (const float*)d_in[17];
    const float* bb2 = (const float*)d_in[18];
    const float* a2  = (const float*)d_in[19];
    const float* We3 = (const float*)d_in[20];
    const float* be3 = (const float*)d_in[21];
    const float* bias3 = (const float*)d_in[22];
    const float* Wr3 = (const float*)d_in[23];
    const float* br3 = (const float*)d_in[24];
    const float* bg3 = (const float*)d_in[25];
    const float* bb3 = (const float*)d_in[26];
    const float* a3  = (const float*)d_in[27];
    const float* Wi  = (const float*)d_in[28];
    const float* bi  = (const float*)d_in[29];
    const float* Wj  = (const float*)d_in[30];
    const float* bj  = (const float*)d_in[31];
    const float* Wfc = (const float*)d_in[32];
    const float* bfc = (const float*)d_in[33];
    float* ws  = (float*)d_ws;
    float* out = (float*)d_out;

    hipMemsetAsync(d_ws, 0, (size_t)ZERO_FLOATS * sizeof(float), stream);
    k_prep<<<442, 256, 0, stream>>>(We1, be1, We2, be2, We3, be3, ei, ws);

    // layer 1: cin=16, cout=32, Ncols=288
    k_proj<16><<<dim3(64, 5), 256, 0, stream>>>(x, ws + OFF_WC1, ws + OFF_DEG, ws + OFF_Y, 288);
    k_egather<32><<<NE * 32 / 256, 256, 0, stream>>>(ws + OFF_Y, eattr, ei, ws + OFF_H1);
    k_node<16, 32, 8><<<NN / 64, 256, 0, stream>>>(x, Wr1, br1, bias1, ws + OFF_H1, ws + OFF_ST1);
    k_bn<32><<<NN * 32 / 256, 256, 0, stream>>>(ws + OFF_H1, ws + OFF_ST1, bg1, bb1, a1);

    // layer 2: cin=32, cout=64, Ncols=576
    k_proj<32><<<dim3(64, 9), 256, 0, stream>>>(ws + OFF_H1, ws + OFF_WC2, ws + OFF_DEG, ws + OFF_Y, 576);
    k_egather<64><<<NE * 64 / 256, 256, 0, stream>>>(ws + OFF_Y, eattr, ei, ws + OFF_H2);
    k_node<32, 64, 8><<<NN / 32, 256, 0, stream>>>(ws + OFF_H1, Wr2, br2, bias2, ws + OFF_H2, ws + OFF_ST2);
    k_bn<64><<<NN * 64 / 256, 256, 0, stream>>>(ws + OFF_H2, ws + OFF_ST2, bg2, bb2, a2);

    // layer 3: cin=64, cout=128, Ncols=1152
    k_proj<64><<<dim3(64, 18), 256, 0, stream>>>(ws + OFF_H2, ws + OFF_WC3, ws + OFF_DEG, ws + OFF_Y, 1152);
    k_egather<128><<<NE * 128 / 256, 256, 0, stream>>>(ws + OFF_Y, eattr, ei, ws + OFF_H3);
    k_node<64, 128, 8><<<NN / 16, 256, 0, stream>>>(ws + OFF_H2, Wr3, br3, bias3, ws + OFF_H3, ws + OFF_ST3);
    k_bn<128><<<NN * 128 / 256, 256, 0, stream>>>(ws + OFF_H3, ws + OFF_ST3, bg3, bb3, a3);

    // pooling + head
    k_pool<<<NN / 16, 256, 0, stream>>>(ws + OFF_H3, batch, Wi, bi, Wj, bj, ws + OFF_POOL);
    k_final<<<NG, 256, 0, stream>>>(ws + OFF_POOL, Wfc, bfc, out);
}